// Round 1
// 256.539 us; speedup vs baseline: 1.0670x; 1.0670x over previous
//
#include <hip/hip_runtime.h>
#include <stdint.h>

// DetectPeaksTM: per row of nt=8192 fp32, x=|xcorr|, sliding max window K=301
// (pad 150), scores = x where x==windowmax else 0, top-2 (score, idx).
// Outputs concatenated: [nrows*2] f32 scores, then [nrows*2] indices written
// as float values (harness reads whole d_out as float32; idx<8192 exact).
//
// R7: coalesced-load + swizzled-LDS restage (R6 was segment-per-thread with
// 16B/lane @128B-stride global loads = 64 line-requests/instr, ~5.2 TB/s).
//  P0: lane s instr j loads g4[j*256+s] -> 1KiB contiguous per wave-instr
//      (16 line-requests/instr), nontemporal (row is read exactly once).
//      abs applied, stored to LDS float4-slot q = p ^ ((p>>3)&7): both the
//      write pattern and the P1 readback hit each 4-bank group exactly
//      8x/wave = structural minimum (conflict-free).
//  P1: thread s reads back its 32 consecutive elems (8x ds_read_b128,
//      swizzled), in-register segmax, one ds_write of m[s].
//  P2a: 9 neighbor segmaxes m[s-4..s+4]; segs s-3..s+3 lie inside EVERY
//       +-150 window of seg s, so sval >= max(m[s-3..s+3]) rejects ~6/7.
//  P2b: survivors only: tier1 interior-seg max from the 9 cached regs,
//       tier2 exact edge check from the LDS-resident |row| (no global
//       re-reads, values already abs).
//  P3: top-2 via monotone key (bits(v)<<32)|(8191-t) (value desc, idx asc
//      on ties == jax.lax.top_k order), wave shuffle + tiny LDS reduce.

#define NT 8192
#define RADIUS 150
#define NSEG 256
#define NF4 2048

typedef float f4 __attribute__((ext_vector_type(4)));

__global__ __launch_bounds__(256) void detect_peaks_kernel(
    const float* __restrict__ x, float* __restrict__ out, int nrows)
{
    const int row = blockIdx.x;
    const int s = threadIdx.x;                 // this thread's segment

    __shared__ f4 lds4[NF4];                   // swizzled |row| (32 KiB)
    __shared__ float mm[8 + NSEG + 16];        // zero-padded seg maxes
    __shared__ unsigned long long wred[8];
    float* const mmp = mm + 8;

    const f4* g4 = (const f4*)(x + (size_t)row * NT);

    if (s < 8) mm[s] = 0.0f;
    if (s < 16) mm[8 + NSEG + s] = 0.0f;

    // ---- P0: fully-coalesced streaming load, abs, swizzled LDS store ----
    f4 ld[8];
#pragma unroll
    for (int j = 0; j < 8; ++j)
        ld[j] = __builtin_nontemporal_load(g4 + j * 256 + s);
    const int wsw = (s >> 3) & 7;              // ((p>>3)&7) with p=j*256+s
#pragma unroll
    for (int j = 0; j < 8; ++j) {
        f4 v = ld[j];
        v.x = fabsf(v.x); v.y = fabsf(v.y);
        v.z = fabsf(v.z); v.w = fabsf(v.w);
        lds4[(j * 256 + s) ^ wsw] = v;
    }
    __syncthreads();

    // ---- P1: own-segment readback (conflict-free), in-register segmax ----
    f4 vv[8];
    const int rsw = s & 7;                     // ((p>>3)&7) with p=s*8+j
#pragma unroll
    for (int j = 0; j < 8; ++j) vv[j] = lds4[(s * 8 + j) ^ rsw];

    float sval = 0.0f;
#pragma unroll
    for (int j = 0; j < 8; ++j) {
        f4 v = vv[j];
        sval = fmaxf(sval, fmaxf(fmaxf(v.x, v.y), fmaxf(v.z, v.w)));
    }
    mmp[s] = sval;
    __syncthreads();

    // ---- P2a: neighbor prefilter ----
    float nbr[9];                              // m[s-4 .. s+4]
#pragma unroll
    for (int j = 0; j < 9; ++j) nbr[j] = mmp[s - 4 + j];
    float nb7 = 0.0f;
#pragma unroll
    for (int j = 1; j <= 7; ++j) nb7 = fmaxf(nb7, nbr[j]);   // s-3..s+3

    unsigned long long k1 = 0ull, k2 = 0ull;

    if (!(nb7 > sval)) {
        // ---- P2b: survivor -- enumerate ties, exact verification ----
        unsigned eqm = 0u;
#pragma unroll
        for (int j = 0; j < 8; ++j) {
            eqm |= (vv[j].x == sval ? 1u : 0u) << (4 * j + 0);
            eqm |= (vv[j].y == sval ? 1u : 0u) << (4 * j + 1);
            eqm |= (vv[j].z == sval ? 1u : 0u) << (4 * j + 2);
            eqm |= (vv[j].w == sval ? 1u : 0u) << (4 * j + 3);
        }
        while (eqm) {
            const int b = __builtin_ctz(eqm); eqm &= (eqm - 1u);
            const int t = (s << 5) + b;
            const int l = max(t - RADIUS, 0);
            const int r = min(t + RADIUS, NT - 1);
            const int il = l >> 5, ir = r >> 5;   // il in {s-5,s-4}, ir in {s+4,s+5}
            // tier1: interior segs [il+1, ir-1] subset of [s-4, s+4] -> regs
            float im = 0.0f;
#pragma unroll
            for (int j = 0; j < 9; ++j) {
                const int seg = s - 4 + j;
                im = fmaxf(im, (seg >= il + 1 && seg <= ir - 1) ? nbr[j] : 0.0f);
            }
            if (im > sval) continue;              // beaten inside window
            // tier2: exact edge check from LDS-resident |row| (already abs)
            float em = 0.0f;
            {   // head [l, (il+1)*32): blocks l>>2 .. il*8+7, j==0 partial
                const int hb0 = l >> 2;
                const int hbN = il * 8 + 8;
#pragma unroll
                for (int j = 0; j < 8; ++j) {
                    const int bb = hb0 + j;
                    const f4 q = lds4[bb ^ ((bb >> 3) & 7)];
                    float bm;
                    if (j == 0) {
                        bm = (4 * bb + 0 >= l) ? q.x : 0.0f;
                        bm = fmaxf(bm, (4 * bb + 1 >= l) ? q.y : 0.0f);
                        bm = fmaxf(bm, (4 * bb + 2 >= l) ? q.z : 0.0f);
                        bm = fmaxf(bm, q.w);         // 4bb+3 >= l always
                    } else {
                        bm = fmaxf(fmaxf(q.x, q.y), fmaxf(q.z, q.w));
                    }
                    em = fmaxf(em, (bb < hbN) ? bm : 0.0f);
                }
            }
            {   // tail [ir*32, r]: blocks ir*8 .. ir*8+7, elem-masked by <= r
                const int tb0 = ir * 8;
#pragma unroll
                for (int j = 0; j < 8; ++j) {
                    const int bb = tb0 + j;
                    const f4 q = lds4[bb ^ ((bb >> 3) & 7)];
                    float bm;
                    bm = (4 * bb + 0 <= r) ? q.x : 0.0f;
                    bm = fmaxf(bm, (4 * bb + 1 <= r) ? q.y : 0.0f);
                    bm = fmaxf(bm, (4 * bb + 2 <= r) ? q.z : 0.0f);
                    bm = fmaxf(bm, (4 * bb + 3 <= r) ? q.w : 0.0f);
                    em = fmaxf(em, bm);
                }
            }
            if (em > sval) continue;
            const unsigned long long key =
                ((unsigned long long)__float_as_uint(sval) << 32) |
                (unsigned)(NT - 1 - t);
            if (key > k1) { k2 = k1; k1 = key; }
            else if (key > k2) { k2 = key; }
        }
    }

    // ---- P3: top-2 reduction (wave shuffle, then 4 waves via LDS) ----
#pragma unroll
    for (int off = 32; off >= 1; off >>= 1) {
        unsigned long long o1 = __shfl_down(k1, off);
        unsigned long long o2 = __shfl_down(k2, off);
        unsigned long long hi = (k1 > o1) ? k1 : o1;
        unsigned long long lo = (k1 > o1) ? o1 : k1;
        unsigned long long s2 = (k2 > o2) ? k2 : o2;
        k1 = hi;
        k2 = (lo > s2) ? lo : s2;
    }
    const int wave = s >> 6;
    if ((s & 63) == 0) { wred[wave * 2] = k1; wred[wave * 2 + 1] = k2; }
    __syncthreads();

    if (s == 0) {
        unsigned long long a1 = wred[0], a2 = wred[1];
        for (int wv = 1; wv < 4; ++wv) {
            unsigned long long o1 = wred[wv * 2], o2 = wred[wv * 2 + 1];
            unsigned long long hi = (a1 > o1) ? a1 : o1;
            unsigned long long lo = (a1 > o1) ? o1 : a1;
            unsigned long long s2 = (a2 > o2) ? a2 : o2;
            a1 = hi;
            a2 = (lo > s2) ? lo : s2;
        }
        float s1v, s2v; int i1, i2;
        if (a1 == 0ull) { s1v = 0.0f; i1 = 0; }
        else {
            s1v = __uint_as_float((unsigned)(a1 >> 32));
            i1 = (NT - 1) - (int)(a1 & 0xffffffffull);
        }
        if (a2 == 0ull) {   // <2 peaks: second entry is first zero-score slot
            s2v = 0.0f;
            i2 = (i1 == 0) ? 1 : 0;
        } else {
            s2v = __uint_as_float((unsigned)(a2 >> 32));
            i2 = (NT - 1) - (int)(a2 & 0xffffffffull);
        }
        out[row * 2 + 0] = s1v;
        out[row * 2 + 1] = s2v;
        float* oi = out + (size_t)nrows * 2;
        oi[row * 2 + 0] = (float)i1;
        oi[row * 2 + 1] = (float)i2;
    }
}

extern "C" void kernel_launch(void* const* d_in, const int* in_sizes, int n_in,
                              void* d_out, int out_size, void* d_ws, size_t ws_size,
                              hipStream_t stream) {
    const float* x = (const float*)d_in[0];
    // d_in[1] = nlag (unused by the reference)
    float* out = (float*)d_out;
    const int nrows = in_sizes[0] / NT;      // 32*3*64 = 6144
    detect_peaks_kernel<<<nrows, 256, 0, stream>>>(x, out, nrows);
}